// Round 8
// baseline (20158.476 us; speedup 1.0000x reference)
//
#include <hip/hip_runtime.h>

#define TT 2048
#define UU 256
#define N3 768
#define CH 32
#define NCH (TT / CH)        // 64 chunks
#define NTASK (NCH * 4)      // 256 (chunk, rowgroup) tasks

typedef _Float16 f16;
typedef __attribute__((ext_vector_type(8))) _Float16 f16x8;   // 4 VGPRs
typedef __attribute__((ext_vector_type(4))) float     f32x4;

// streams / packed weights (device BSS, deterministic per launch)
__device__ f16   g_xh[(size_t)64 * TT * 32];     // x padded to 32 feats, f16
__device__ f16   g_h1[(size_t)64 * TT * UU];     // layer-1 h stream (seq1, f16)
__device__ float g_xp1[(size_t)64 * TT * N3];    // xp1 stream (bias folded)
__device__ float g_xp2[(size_t)64 * TT * N3];    // xp2 stream (bias folded)
__device__ f16x8 g_Uf1[384 * 64];                // B-frags: [(w*3+g)*8+kt][lane]
__device__ f16x8 g_Uf2[384 * 64];
__device__ f16x8 g_W2f[384 * 64];
__device__ f16x8 g_W1f[48 * 64];                 // K=32 zero-padded

// flags in d_ws: [0,256) xp1_ready, [256,512) h1_ready, [512,768) xp2_ready
// index i = chunk*4 + rg ; value 1 when ready (d_ws poisoned negative)

__device__ __forceinline__ f32x4 mf(f16x8 a, f16x8 b, f32x4 c) {
    return __builtin_amdgcn_mfma_f32_16x16x32_f16(a, b, c, 0, 0, 0);
}

// ---- pack [256][768] fp32 -> B-frags (wave w: cols g*256 + w*16 + c) ------
__global__ __launch_bounds__(256) void pack256(const float* __restrict__ M,
                                               f16x8* __restrict__ out) {
    int idx = blockIdx.x * 256 + threadIdx.x;    // [0, 384*64)
    int f = idx >> 6, lane = idx & 63;
    int w = f / 24, g = (f / 8) % 3, kt = f & 7;
    int q = lane >> 4, c = lane & 15;
    int col = g * 256 + w * 16 + c;
    f16x8 v;
#pragma unroll
    for (int j = 0; j < 8; j++) v[j] = (f16)M[(kt * 32 + q * 8 + j) * N3 + col];
    out[idx] = v;
}

__global__ __launch_bounds__(256) void pack_w1(const float* __restrict__ M,
                                               f16x8* __restrict__ out) {
    int idx = blockIdx.x * 256 + threadIdx.x;    // [0, 48*64)
    int f = idx >> 6, lane = idx & 63;
    int w = f / 3, g = f % 3;
    int q = lane >> 4, c = lane & 15;
    int col = g * 256 + w * 16 + c;
    f16x8 v;
#pragma unroll
    for (int j = 0; j < 8; j++) {
        int k = q * 8 + j;
        v[j] = (k < 15) ? (f16)M[k * N3 + col] : (f16)0.f;
    }
    out[idx] = v;
}

__global__ __launch_bounds__(256) void pack_x(const float* __restrict__ x,
                                              f16* __restrict__ xh) {
    int i = blockIdx.x * 256 + threadIdx.x;      // [0, 64*2048)
    const float* s = x + (size_t)i * 15;
    f16 tmp[32];
#pragma unroll
    for (int k = 0; k < 15; k++) tmp[k] = (f16)s[k];
#pragma unroll
    for (int k = 15; k < 32; k++) tmp[k] = (f16)0.f;
    f16x8* d = (f16x8*)(xh + (size_t)i * 32);
#pragma unroll
    for (int m = 0; m < 4; m++) d[m] = *(f16x8*)&tmp[m * 8];
}

// ---- fused pipeline: 104 WGs x 1024 thr ------------------------------------
// WG 0-3: L1 recurrence (rg) | 4-7: L2 recurrence | 8-23: xp1 workers |
// 24-103: xp2 workers. Streams published with agent-scope atomic stores;
// consumers use plain loads AFTER flag acquire (write-once-read-later).
__global__ __launch_bounds__(1024) void gru_pipe(
    const float* __restrict__ b1, const float* __restrict__ b2,
    float* __restrict__ out, int* __restrict__ flags)
{
    __shared__ __align__(16) f16 hbuf[2][16][264];   // 16896 B double-buffer
    const int bid = blockIdx.x, tid = threadIdx.x;
    const int w = tid >> 6, lane = tid & 63, q = lane >> 4, c = lane & 15;
    const int j0 = w * 16 + c;

    if (bid < 8) {
        // ================= recurrence =================
        const int layer = bid >> 2, rg = bid & 3;
        const f16x8* Uf = layer ? g_Uf2 : g_Uf1;
        const float* bb = layer ? b2 : b1;
        const float* xps = layer ? g_xp2 : g_xp1;
        int* cons = flags + (layer ? 512 : 0);

        f16x8 uf[3][8];
#pragma unroll
        for (int g = 0; g < 3; g++)
#pragma unroll
            for (int kt = 0; kt < 8; kt++) {
                uf[g][kt] = Uf[((w * 3 + g) * 8 + kt) * 64 + lane];
                asm volatile("" : "+v"(uf[g][kt]));
            }
        const float brec3 = bb[N3 + 512 + j0];
        float h_old[4] = {0.f, 0.f, 0.f, 0.f};
        for (int i = tid; i < 4224; i += 1024) ((unsigned*)hbuf)[i] = 0;
        __syncthreads();

        const char* xpr = (const char*)(xps + (size_t)rg * 16 * TT * N3);
        unsigned vrow[4];
#pragma unroll
        for (int r = 0; r < 4; r++)
            vrow[r] = ((unsigned)(q * 4 + r) * TT * N3 + (unsigned)j0) * 4u;
        f16* h1rg = g_h1 + (size_t)rg * 16 * TT * UU;
        long bud = 1L << 22;

        for (int t = 0; t < TT; t++) {
            if ((t & (CH - 1)) == 0) {
                if (tid == 0) {
                    int* f = cons + (t >> 5) * 4 + rg;
                    while (bud > 0 && __hip_atomic_load(f, __ATOMIC_ACQUIRE,
                           __HIP_MEMORY_SCOPE_AGENT) < 1) bud--;
                }
                __syncthreads();
            }
            const char* xpt = xpr + (size_t)t * N3 * 4;
            f32x4 az, ar;
            float xph[4];
#pragma unroll
            for (int r = 0; r < 4; r++) az[r]  = *(const float*)(xpt + vrow[r]);
#pragma unroll
            for (int r = 0; r < 4; r++) ar[r]  = *(const float*)(xpt + vrow[r] + 1024);
#pragma unroll
            for (int r = 0; r < 4; r++) xph[r] = *(const float*)(xpt + vrow[r] + 2048);
            f32x4 ah = {brec3, brec3, brec3, brec3};

            const char* hb = (const char*)hbuf + (t & 1) * 8448
                           + (unsigned)(c * 528 + q * 16);
#pragma unroll
            for (int kt = 0; kt < 8; kt++) {
                f16x8 a = *(const f16x8*)(hb + kt * 64);
                ah = mf(a, uf[2][kt], ah);   // no load dep: issues first
                az = mf(a, uf[0][kt], az);
                ar = mf(a, uf[1][kt], ar);
            }

            char* hw = (char*)hbuf + ((t & 1) ^ 1) * 8448 + (unsigned)(j0 * 2);
            f16* h1t = h1rg + (size_t)t * UU;
#pragma unroll
            for (int r = 0; r < 4; r++) {
                float z  = 1.f / (1.f + __expf(-az[r]));
                float rr = 1.f / (1.f + __expf(-ar[r]));
                float hh = xph[r] + rr * ah[r];
                hh = hh > 0.f ? hh : 0.f;
                float hn = z * h_old[r] + (1.f - z) * hh;
                h_old[r] = hn;
                *(f16*)(hw + (q * 4 + r) * 528) = (f16)hn;
                if (layer == 0) {
                    float hp = __shfl_xor(hn, 1);
                    if (!(c & 1)) {
                        union { f16 h[2]; unsigned u; } pk;
                        pk.h[0] = (f16)hn; pk.h[1] = (f16)hp;
                        unsigned off = ((unsigned)(q * 4 + r) * TT * UU + (unsigned)j0) * 2u;
                        __hip_atomic_store((unsigned*)((char*)h1t + off), pk.u,
                                           __ATOMIC_RELAXED, __HIP_MEMORY_SCOPE_AGENT);
                    }
                }
            }
            __syncthreads();
            if (layer == 0 && (t & (CH - 1)) == (CH - 1)) {
                if (tid == 0)
                    __hip_atomic_store(flags + 256 + (t >> 5) * 4 + rg, 1,
                                       __ATOMIC_RELEASE, __HIP_MEMORY_SCOPE_AGENT);
            }
        }
#pragma unroll
        for (int r = 0; r < 4; r++) {
            int b = rg * 16 + q * 4 + r;
            float hn = h_old[r];
            if (layer == 0) out[16384 + b * UU + j0] = hn;           // state1
            else { out[b * UU + j0] = hn; out[32768 + b * UU + j0] = hn; }
        }
    } else if (bid < 24) {
        // ================= xp1 workers: x @ W1 + bias =================
        const int wid = bid - 8;
        f16x8 wf[3];
#pragma unroll
        for (int g = 0; g < 3; g++) wf[g] = g_W1f[(w * 3 + g) * 64 + lane];
        const float bz = b1[j0] + b1[N3 + j0];
        const float br_ = b1[256 + j0] + b1[N3 + 256 + j0];
        const float bh = b1[512 + j0];
        for (int i = wid; i < NTASK; i += 16) {
            int cch = i >> 2, rg = i & 3;
            for (int mt = 0; mt < 32; mt++) {
                int b = rg * 16 + (mt >> 1), t0 = cch * 32 + (mt & 1) * 16;
                f16x8 a = *(const f16x8*)(g_xh + ((size_t)b * TT + t0 + c) * 32 + q * 8);
                f32x4 az = {bz, bz, bz, bz}, ar2 = {br_, br_, br_, br_}, ah = {bh, bh, bh, bh};
                az = mf(a, wf[0], az); ar2 = mf(a, wf[1], ar2); ah = mf(a, wf[2], ah);
                float* xpb = g_xp1 + ((size_t)b * TT + t0) * N3;
#pragma unroll
                for (int r = 0; r < 4; r++) {
                    float* p = xpb + (size_t)(q * 4 + r) * N3 + j0;
                    __hip_atomic_store(p,       az[r],  __ATOMIC_RELAXED, __HIP_MEMORY_SCOPE_AGENT);
                    __hip_atomic_store(p + 256, ar2[r], __ATOMIC_RELAXED, __HIP_MEMORY_SCOPE_AGENT);
                    __hip_atomic_store(p + 512, ah[r],  __ATOMIC_RELAXED, __HIP_MEMORY_SCOPE_AGENT);
                }
            }
            __syncthreads();
            if (tid == 0)
                __hip_atomic_store(flags + i, 1, __ATOMIC_RELEASE, __HIP_MEMORY_SCOPE_AGENT);
        }
    } else {
        // ================= xp2 workers: h1seq @ W2 + bias =================
        const int wid = bid - 24;
        f16x8 wf[3][8];
#pragma unroll
        for (int g = 0; g < 3; g++)
#pragma unroll
            for (int kt = 0; kt < 8; kt++) {
                wf[g][kt] = g_W2f[((w * 3 + g) * 8 + kt) * 64 + lane];
                asm volatile("" : "+v"(wf[g][kt]));
            }
        const float bz = b2[j0] + b2[N3 + j0];
        const float br_ = b2[256 + j0] + b2[N3 + 256 + j0];
        const float bh = b2[512 + j0];
        long bud = 1L << 22;
        for (int i = wid; i < NTASK; i += 80) {
            if (tid == 0) {
                int* f = flags + 256 + i;
                while (bud > 0 && __hip_atomic_load(f, __ATOMIC_ACQUIRE,
                       __HIP_MEMORY_SCOPE_AGENT) < 1) bud--;
            }
            __syncthreads();
            int cch = i >> 2, rg = i & 3;
            for (int mt = 0; mt < 32; mt++) {
                int b = rg * 16 + (mt >> 1), t0 = cch * 32 + (mt & 1) * 16;
                const f16* ab = g_h1 + ((size_t)b * TT + t0 + c) * UU;
                f32x4 az = {bz, bz, bz, bz}, ar2 = {br_, br_, br_, br_}, ah = {bh, bh, bh, bh};
#pragma unroll
                for (int kt = 0; kt < 8; kt++) {
                    f16x8 a = *(const f16x8*)(ab + kt * 32 + q * 8);
                    az = mf(a, wf[0][kt], az); ar2 = mf(a, wf[1][kt], ar2); ah = mf(a, wf[2][kt], ah);
                }
                float* xpb = g_xp2 + ((size_t)b * TT + t0) * N3;
#pragma unroll
                for (int r = 0; r < 4; r++) {
                    float* p = xpb + (size_t)(q * 4 + r) * N3 + j0;
                    __hip_atomic_store(p,       az[r],  __ATOMIC_RELAXED, __HIP_MEMORY_SCOPE_AGENT);
                    __hip_atomic_store(p + 256, ar2[r], __ATOMIC_RELAXED, __HIP_MEMORY_SCOPE_AGENT);
                    __hip_atomic_store(p + 512, ah[r],  __ATOMIC_RELAXED, __HIP_MEMORY_SCOPE_AGENT);
                }
            }
            __syncthreads();
            if (tid == 0)
                __hip_atomic_store(flags + 512 + i, 1, __ATOMIC_RELEASE, __HIP_MEMORY_SCOPE_AGENT);
        }
    }
}

extern "C" void kernel_launch(void* const* d_in, const int* in_sizes, int n_in,
                              void* d_out, int out_size, void* d_ws, size_t ws_size,
                              hipStream_t stream) {
    const float* x  = (const float*)d_in[0];
    const float* W1 = (const float*)d_in[1];
    const float* U1 = (const float*)d_in[2];
    const float* b1 = (const float*)d_in[3];
    const float* W2 = (const float*)d_in[4];
    const float* U2 = (const float*)d_in[5];
    const float* b2 = (const float*)d_in[6];
    float* out = (float*)d_out;

    f16x8* Uf1; hipGetSymbolAddress((void**)&Uf1, HIP_SYMBOL(g_Uf1));
    f16x8* Uf2; hipGetSymbolAddress((void**)&Uf2, HIP_SYMBOL(g_Uf2));
    f16x8* W2f; hipGetSymbolAddress((void**)&W2f, HIP_SYMBOL(g_W2f));
    f16x8* W1f; hipGetSymbolAddress((void**)&W1f, HIP_SYMBOL(g_W1f));
    f16*   xh;  hipGetSymbolAddress((void**)&xh,  HIP_SYMBOL(g_xh));

    pack256<<<96, 256, 0, stream>>>(U1, Uf1);
    pack256<<<96, 256, 0, stream>>>(U2, Uf2);
    pack256<<<96, 256, 0, stream>>>(W2, W2f);
    pack_w1<<<12, 256, 0, stream>>>(W1, W1f);
    pack_x<<<512, 256, 0, stream>>>(x, xh);

    gru_pipe<<<104, 1024, 0, stream>>>(b1, b2, out, (int*)d_ws);
}